// Round 2
// baseline (218.380 us; speedup 1.0000x reference)
//
#include <hip/hip_runtime.h>
#include <hip/hip_bf16.h>
#include <math.h>

#define B 4
#define L 2048
#define D 256
#define H 8
#define HD 32
#define SCALE 0.17677669529663687f

typedef __attribute__((ext_vector_type(8))) short short8;
typedef __attribute__((ext_vector_type(4))) float f32x4;

__device__ inline short f2bf(float x) {
  union { float f; unsigned u; } c; c.f = x;
  unsigned r = (c.u + 0x7FFFu + ((c.u >> 16) & 1u)) >> 16;
  return (short)r;
}
__device__ inline unsigned pk2(float a, float b) {
  return ((unsigned)(unsigned short)f2bf(a)) | (((unsigned)(unsigned short)f2bf(b)) << 16);
}

// ---------------- Prep: transpose-convert W [256, N] f32 -> WT [N, 256] bf16
__global__ void prep_wt(const float* __restrict__ w, short* __restrict__ wt, int N) {
  int k = blockIdx.x;        // 0..255
  int n = threadIdx.x;       // 0..N-1
  wt[n * 256 + k] = f2bf(w[k * N + n]);
}

// ---------------- Kernel 1: qkv = x @ Wqkv, head-split outputs --------------
// x: [8192, 256] f32, wt: [768, 256] bf16 (W^T)
// qb/kb: [B*H, L, HD] bf16 ; vt: [B*H, HD, L] bf16 (V transposed)
__global__ __launch_bounds__(64) void qkv_gemm(const float* __restrict__ x,
                                               const short* __restrict__ wt,
                                               short* __restrict__ qb,
                                               short* __restrict__ kb,
                                               short* __restrict__ vt) {
  int bid = blockIdx.x;
  int nt = bid % 48;    // 768 / 16 n-tiles
  int mt = bid / 48;    // 8192 / 64 m-blocks
  int m0 = mt * 64, n0 = nt * 16;
  int l = threadIdx.x;
  int ra = l & 15, g = l >> 4;

  f32x4 acc[4] = {};
  for (int k0 = 0; k0 < 256; k0 += 32) {
    int kk = k0 + g * 8;
    short8 bfrag = *reinterpret_cast<const short8*>(&wt[(n0 + ra) * 256 + kk]);
#pragma unroll
    for (int m = 0; m < 4; ++m) {
      const float* ap = x + (m0 + m * 16 + ra) * 256 + kk;
      f32x4 a0 = *reinterpret_cast<const f32x4*>(ap);
      f32x4 a1 = *reinterpret_cast<const f32x4*>(ap + 4);
      short8 afrag;
#pragma unroll
      for (int j = 0; j < 4; ++j) { afrag[j] = f2bf(a0[j]); afrag[4 + j] = f2bf(a1[j]); }
      acc[m] = __builtin_amdgcn_mfma_f32_16x16x32_bf16(afrag, bfrag, acc[m], 0, 0, 0);
    }
  }

  int n = n0 + ra;
  int which = n >> 8;   // 0=q 1=k 2=v
  int c = n & 255;
  int h = c >> 5, d = c & 31;
#pragma unroll
  for (int m = 0; m < 4; ++m) {
#pragma unroll
    for (int r = 0; r < 4; ++r) {
      int mm = m0 + m * 16 + g * 4 + r;
      int b = mm >> 11, lpos = mm & 2047;
      short val = f2bf(acc[m][r]);
      if (which == 2) {
        vt[((b * H + h) * HD + d) * L + lpos] = val;            // V^T layout
      } else {
        short* dst = (which == 0) ? qb : kb;
        dst[((b * H + h) * L + lpos) * HD + d] = val;
      }
    }
  }
}

// ---------------- Kernel 2: flash attention, swapped-operand S^T/O^T --------
// 4 independent waves per block, each owns one 16-row q-tile.
__global__ __launch_bounds__(256) void attn_fwd(const short* __restrict__ qb,
                                                const short* __restrict__ kb,
                                                const short* __restrict__ vt,
                                                const float* __restrict__ bias,
                                                short* __restrict__ ob) {
  int wid = threadIdx.x >> 6;
  int l = threadIdx.x & 63;
  int gq = blockIdx.x * 4 + wid;       // global wave id, 0..4095
  int bh = gq >> 7;                    // 0..31  (consecutive waves share bh -> K/V L2 reuse)
  int qt = gq & 127;
  int q0 = qt * 16;
  int ra = l & 15, g = l >> 4;

  __shared__ short pt[4][16][40];      // per-wave P^T exchange buffer, padded row (80B)
  short* myp = &pt[wid][0][0];

  // Q as B-fragment: B[k][q] = Q[q0+ra][g*8+j]
  short8 bq = *reinterpret_cast<const short8*>(&qb[(bh * L + q0 + ra) * HD + g * 8]);

  const short* kbase = kb + bh * L * HD;
  const short* vbase = vt + bh * HD * L;
  const float* brow = bias + (long)(q0 + ra) * L;

  f32x4 o0 = {}, o1 = {};              // O^T: lane holds d = g*4+r (o0), 16+g*4+r (o1), q = ra
  f32x4 zf = {};
  float mrun = -1e30f, lsum = 0.f;     // per-lane: owns q = q0 + ra

  for (int kv = 0; kv < L; kv += 32) {
    // K as A-fragment: A[kv_row][k]
    short8 ak0 = *reinterpret_cast<const short8*>(&kbase[(kv + ra) * HD + g * 8]);
    short8 ak1 = *reinterpret_cast<const short8*>(&kbase[(kv + 16 + ra) * HD + g * 8]);
    f32x4 s0 = __builtin_amdgcn_mfma_f32_16x16x32_bf16(ak0, bq, zf, 0, 0, 0);
    f32x4 s1 = __builtin_amdgcn_mfma_f32_16x16x32_bf16(ak1, bq, zf, 0, 0, 0);
    // s0[r] = S^T[kv + g*4+r][q0+ra],  s1[r] = S^T[kv+16+g*4+r][q0+ra]

    f32x4 b0 = *reinterpret_cast<const f32x4*>(&brow[kv + g * 4]);
    f32x4 b1 = *reinterpret_cast<const f32x4*>(&brow[kv + 16 + g * 4]);

    float v[8];
#pragma unroll
    for (int r = 0; r < 4; ++r) {
      v[r] = s0[r] * SCALE + b0[r];
      v[4 + r] = s1[r] * SCALE + b1[r];
    }
    float pm = v[0];
#pragma unroll
    for (int i = 1; i < 8; ++i) pm = fmaxf(pm, v[i]);
    pm = fmaxf(pm, __shfl_xor(pm, 16));
    pm = fmaxf(pm, __shfl_xor(pm, 32));
    float mnew = fmaxf(mrun, pm);
    float alpha = __expf(mrun - mnew);
    float p[8];
#pragma unroll
    for (int i = 0; i < 8; ++i) p[i] = __expf(v[i] - mnew);
    float rs = 0.f;
#pragma unroll
    for (int i = 0; i < 8; ++i) rs += p[i];
    rs += __shfl_xor(rs, 16);
    rs += __shfl_xor(rs, 32);
    lsum = lsum * alpha + rs;
    mrun = mnew;
#pragma unroll
    for (int r = 0; r < 4; ++r) { o0[r] *= alpha; o1[r] *= alpha; }

    // P^T exchange through LDS (wave-local, padded rows -> conflict-free)
    uint2 wa; wa.x = pk2(p[0], p[1]); wa.y = pk2(p[2], p[3]);
    uint2 wb; wb.x = pk2(p[4], p[5]); wb.y = pk2(p[6], p[7]);
    *reinterpret_cast<uint2*>(&myp[ra * 40 + g * 4]) = wa;        // kv cols g*4..g*4+3
    *reinterpret_cast<uint2*>(&myp[ra * 40 + 16 + g * 4]) = wb;   // kv cols 16+g*4..
    short8 pb = *reinterpret_cast<short8*>(&myp[ra * 40 + g * 8]); // B-frag: P^T[kv][q]

    // V^T as A-fragment: A[d][kv]
    short8 va0 = *reinterpret_cast<const short8*>(&vbase[ra * L + kv + g * 8]);
    short8 va1 = *reinterpret_cast<const short8*>(&vbase[(16 + ra) * L + kv + g * 8]);
    o0 = __builtin_amdgcn_mfma_f32_16x16x32_bf16(va0, pb, o0, 0, 0, 0);
    o1 = __builtin_amdgcn_mfma_f32_16x16x32_bf16(va1, pb, o1, 0, 0, 0);
  }

  int b = bh >> 3, h = bh & 7;
  float inv = 1.0f / lsum;
  int row = (b * L + q0 + ra) * D + h * HD;
#pragma unroll
  for (int r = 0; r < 4; ++r) {
    ob[row + g * 4 + r] = f2bf(o0[r] * inv);
    ob[row + 16 + g * 4 + r] = f2bf(o1[r] * inv);
  }
}

// ---------------- Kernel 3: out = O @ Wout ----------------------------------
// ob: [8192, 256] bf16, wt: [256, 256] bf16 (W^T), out: [8192, 256] f32
__global__ __launch_bounds__(64) void out_gemm(const short* __restrict__ ob,
                                               const short* __restrict__ wt,
                                               float* __restrict__ out) {
  int bid = blockIdx.x;
  int nt = bid % 16, mt = bid / 16;
  int m0 = mt * 64, n0 = nt * 16;
  int l = threadIdx.x, ra = l & 15, g = l >> 4;

  f32x4 acc[4] = {};
  for (int k0 = 0; k0 < 256; k0 += 32) {
    int kk = k0 + g * 8;
    short8 bfrag = *reinterpret_cast<const short8*>(&wt[(n0 + ra) * 256 + kk]);
#pragma unroll
    for (int m = 0; m < 4; ++m) {
      short8 afrag = *reinterpret_cast<const short8*>(&ob[(m0 + m * 16 + ra) * 256 + kk]);
      acc[m] = __builtin_amdgcn_mfma_f32_16x16x32_bf16(afrag, bfrag, acc[m], 0, 0, 0);
    }
  }
#pragma unroll
  for (int m = 0; m < 4; ++m)
#pragma unroll
    for (int r = 0; r < 4; ++r)
      out[(m0 + m * 16 + g * 4 + r) * 256 + n0 + ra] = acc[m][r];
}

extern "C" void kernel_launch(void* const* d_in, const int* in_sizes, int n_in,
                              void* d_out, int out_size, void* d_ws, size_t ws_size,
                              hipStream_t stream) {
  const float* x    = (const float*)d_in[0];
  const float* bias = (const float*)d_in[1];
  const float* wqkv = (const float*)d_in[2];
  const float* wout = (const float*)d_in[3];
  float* out = (float*)d_out;

  short* qb     = (short*)d_ws;            // [B*H, L, HD]  2M shorts
  short* kb     = qb + B * L * D;          // [B*H, L, HD]  2M
  short* vt     = kb + B * L * D;          // [B*H, HD, L]  2M
  short* ob     = vt + B * L * D;          // [B*L, D]      2M
  short* wqkvT  = ob + B * L * D;          // [768, 256]    192K
  short* woutT  = wqkvT + 768 * 256;       // [256, 256]    64K

  prep_wt<<<dim3(256), dim3(768), 0, stream>>>(wqkv, wqkvT, 768);
  prep_wt<<<dim3(256), dim3(256), 0, stream>>>(wout, woutT, 256);
  qkv_gemm<<<dim3(6144), dim3(64), 0, stream>>>(x, wqkvT, qb, kb, vt);
  attn_fwd<<<dim3(1024), dim3(256), 0, stream>>>(qb, kb, vt, bias, ob);
  out_gemm<<<dim3(2048), dim3(64), 0, stream>>>(ob, woutT, out);
}

// Round 3
// 183.192 us; speedup vs baseline: 1.1921x; 1.1921x over previous
//
#include <hip/hip_runtime.h>
#include <hip/hip_bf16.h>
#include <math.h>

#define B 4
#define L 2048
#define D 256
#define H 8
#define HD 32
#define SCALE 0.17677669529663687f
#define LOG2E 1.4426950408889634f
#define THRT 5.5451774444795623f   // 8 / log2(e): caps P at 2^8

typedef __attribute__((ext_vector_type(8))) short short8;
typedef __attribute__((ext_vector_type(4))) short short4v;
typedef __attribute__((ext_vector_type(4))) float f32x4;

__device__ inline short f2bf(float x) {
  union { float f; unsigned u; } c; c.f = x;
  unsigned r = (c.u + 0x7FFFu + ((c.u >> 16) & 1u)) >> 16;
  return (short)r;
}

// ---------------- prep: x f32 -> bf16 ---------------------------------------
__global__ __launch_bounds__(256) void prep_xb(const float* __restrict__ x,
                                               short* __restrict__ xb) {
  int i = (blockIdx.x * 256 + threadIdx.x) * 8;
  f32x4 a = *reinterpret_cast<const f32x4*>(x + i);
  f32x4 b = *reinterpret_cast<const f32x4*>(x + i + 4);
  short8 o;
#pragma unroll
  for (int j = 0; j < 4; ++j) { o[j] = f2bf(a[j]); o[4 + j] = f2bf(b[j]); }
  *reinterpret_cast<short8*>(xb + i) = o;
}

// ---------------- prep: W [256,N] f32 -> W^T [N,256] bf16 (LDS tiled) -------
__global__ __launch_bounds__(256) void prep_wt(const float* __restrict__ w,
                                               short* __restrict__ wt, int N) {
  __shared__ short tile[32][33];
  int k0 = blockIdx.x * 32;
  int n0 = blockIdx.y * 32;
  int tx = threadIdx.x & 31, ty = threadIdx.x >> 5;   // ty 0..7
#pragma unroll
  for (int i = 0; i < 32; i += 8)
    tile[ty + i][tx] = f2bf(w[(k0 + ty + i) * N + n0 + tx]);
  __syncthreads();
#pragma unroll
  for (int i = 0; i < 32; i += 8)
    wt[(n0 + ty + i) * 256 + k0 + tx] = tile[tx][ty + i];
}

// ---------------- Kernel 1: qkv = xb @ Wqkv, head-split outputs -------------
// xb: [8192,256] bf16, wt: [768,256] bf16; qb/kb: [bh][L][HD]; vt: [bh][HD][L]
__global__ __launch_bounds__(64) void qkv_gemm(const short* __restrict__ xb,
                                               const short* __restrict__ wt,
                                               short* __restrict__ qb,
                                               short* __restrict__ kb,
                                               short* __restrict__ vt) {
  int bid = blockIdx.x;
  int mt = bid / 12, nt = bid % 12;
  int m0 = mt * 64, n0 = nt * 64;
  int l = threadIdx.x, ra = l & 15, g = l >> 4;

  f32x4 acc[4][4] = {};
  for (int k0 = 0; k0 < 256; k0 += 32) {
    int kk = k0 + g * 8;
    short8 bfr[4], afr[4];
#pragma unroll
    for (int nf = 0; nf < 4; ++nf)
      bfr[nf] = *reinterpret_cast<const short8*>(&wt[(n0 + nf * 16 + ra) * 256 + kk]);
#pragma unroll
    for (int mf = 0; mf < 4; ++mf)
      afr[mf] = *reinterpret_cast<const short8*>(&xb[(m0 + mf * 16 + ra) * 256 + kk]);
#pragma unroll
    for (int mf = 0; mf < 4; ++mf)
#pragma unroll
      for (int nf = 0; nf < 4; ++nf)
        acc[mf][nf] = __builtin_amdgcn_mfma_f32_16x16x32_bf16(afr[mf], bfr[nf], acc[mf][nf], 0, 0, 0);
  }

  int sec = n0 >> 8;   // 0=q 1=k 2=v (uniform per block)
#pragma unroll
  for (int nf = 0; nf < 4; ++nf) {
    int n = n0 + nf * 16 + ra;
    int c = n & 255;
    int h = c >> 5, d = c & 31;
#pragma unroll
    for (int mf = 0; mf < 4; ++mf) {
#pragma unroll
      for (int r = 0; r < 4; ++r) {
        int mm = m0 + mf * 16 + g * 4 + r;
        int b = mm >> 11, lpos = mm & 2047;
        short val = f2bf(acc[mf][nf][r]);
        if (sec == 2) vt[((b * H + h) * HD + d) * L + lpos] = val;
        else {
          short* dst = (sec == 0) ? qb : kb;
          dst[((b * H + h) * L + lpos) * HD + d] = val;
        }
      }
    }
  }
}

// ---------------- Kernel 2: flash attention, reg-resident, prefetched -------
__global__ __launch_bounds__(256, 4) void attn_fwd(const short* __restrict__ qb,
                                                   const short* __restrict__ kb,
                                                   const short* __restrict__ vt,
                                                   const float* __restrict__ bias,
                                                   short* __restrict__ ob) {
  int wid = threadIdx.x >> 6;
  int l = threadIdx.x & 63;
  int gq = blockIdx.x * 4 + wid;
  int bh = gq >> 7;
  int qt = gq & 127;
  int q0 = qt * 16;
  int ra = l & 15, g = l >> 4;
  bool oddg = (g & 1);

  const short* kptr = kb + bh * (L * HD) + ra * HD + g * 8;
  const short* vptr0 = vt + bh * (HD * L) + ra * L + g * 8;
  const short* vptr1 = vptr0 + 16 * L;
  const float* brow = bias + (size_t)(q0 + ra) * L + g * 4;

  short8 bq = *reinterpret_cast<const short8*>(qb + (bh * L + q0 + ra) * HD + g * 8);

  f32x4 o0 = {}, o1 = {}, zf = {};
  float mrun = -1e30f, lsum = 0.f;

  short8 akA[4], akB[4];
  f32x4 bbA[4], bbB[4];

  auto LOADT = [&](short8 (&ak)[4], f32x4 (&bb)[4], int kv) {
#pragma unroll
    for (int c = 0; c < 4; ++c)
      ak[c] = *reinterpret_cast<const short8*>(kptr + (kv + 16 * c) * HD);
#pragma unroll
    for (int c = 0; c < 4; ++c)
      bb[c] = *reinterpret_cast<const f32x4*>(brow + kv + 16 * c);
  };

  auto STEP = [&](short8 (&ak)[4], f32x4 (&bb)[4], int kv) {
    // V loads for this tile issued early (hidden under QK + softmax)
    short8 va00 = *reinterpret_cast<const short8*>(vptr0 + kv);
    short8 va01 = *reinterpret_cast<const short8*>(vptr0 + kv + 32);
    short8 va10 = *reinterpret_cast<const short8*>(vptr1 + kv);
    short8 va11 = *reinterpret_cast<const short8*>(vptr1 + kv + 32);

    f32x4 s0 = __builtin_amdgcn_mfma_f32_16x16x32_bf16(ak[0], bq, zf, 0, 0, 0);
    f32x4 s1 = __builtin_amdgcn_mfma_f32_16x16x32_bf16(ak[1], bq, zf, 0, 0, 0);
    f32x4 s2 = __builtin_amdgcn_mfma_f32_16x16x32_bf16(ak[2], bq, zf, 0, 0, 0);
    f32x4 s3 = __builtin_amdgcn_mfma_f32_16x16x32_bf16(ak[3], bq, zf, 0, 0, 0);

    float v[16];
#pragma unroll
    for (int r = 0; r < 4; ++r) {
      v[r]      = fmaf(s0[r], SCALE, bb[0][r]);
      v[4 + r]  = fmaf(s1[r], SCALE, bb[1][r]);
      v[8 + r]  = fmaf(s2[r], SCALE, bb[2][r]);
      v[12 + r] = fmaf(s3[r], SCALE, bb[3][r]);
    }
    float pm = v[0];
#pragma unroll
    for (int i = 1; i < 16; ++i) pm = fmaxf(pm, v[i]);
    pm = fmaxf(pm, __shfl_xor(pm, 16));
    pm = fmaxf(pm, __shfl_xor(pm, 32));

    if (!__all(pm <= mrun + THRT)) {
      float mnew = fmaxf(mrun, pm);
      float al = __expf(mrun - mnew);
      lsum *= al;
#pragma unroll
      for (int r = 0; r < 4; ++r) { o0[r] *= al; o1[r] *= al; }
      mrun = mnew;
    }
    float ms = -mrun * LOG2E;
#pragma unroll
    for (int i = 0; i < 16; ++i) {
      float x = fmaf(v[i], LOG2E, ms);
      asm("v_exp_f32 %0, %1" : "=v"(v[i]) : "v"(x));   // v[i] = 2^x, in-place
    }
    float rs = 0.f;
#pragma unroll
    for (int i = 0; i < 16; ++i) rs += v[i];
    rs += __shfl_xor(rs, 16);
    rs += __shfl_xor(rs, 32);
    lsum += rs;

    // Per 32-kv chunk: pack P to bf16 and assemble the P^T B-fragment in-reg.
#pragma unroll
    for (int ch = 0; ch < 2; ++ch) {
      const float* pc = v + ch * 8;
      unsigned w01, w23, w45, w67;
      asm("v_cvt_pk_bf16_f32 %0, %1, %2" : "=v"(w01) : "v"(pc[0]), "v"(pc[1]));
      asm("v_cvt_pk_bf16_f32 %0, %1, %2" : "=v"(w23) : "v"(pc[2]), "v"(pc[3]));
      asm("v_cvt_pk_bf16_f32 %0, %1, %2" : "=v"(w45) : "v"(pc[4]), "v"(pc[5]));
      asm("v_cvt_pk_bf16_f32 %0, %1, %2" : "=v"(w67) : "v"(pc[6]), "v"(pc[7]));
      // swap rows 32-63 of first with rows 0-31 of second
      asm("v_permlane32_swap_b32 %0, %1" : "+v"(w01), "+v"(w45));
      asm("v_permlane32_swap_b32 %0, %1" : "+v"(w23), "+v"(w67));
      // now per lane: a'=w01, b'=w45, c'=w23, d'=w67 (see derivation)
      unsigned z1 = oddg ? w01 : w45;
      unsigned z2 = oddg ? w23 : w67;
      unsigned y1 = (unsigned)__shfl_xor((int)z1, 16);
      unsigned y2 = (unsigned)__shfl_xor((int)z2, 16);
      union { unsigned u[4]; short8 s; } pb;
      pb.u[0] = oddg ? y1 : w01;
      pb.u[1] = oddg ? y2 : w23;
      pb.u[2] = oddg ? w45 : y1;
      pb.u[3] = oddg ? w67 : y2;
      o0 = __builtin_amdgcn_mfma_f32_16x16x32_bf16(ch ? va01 : va00, pb.s, o0, 0, 0, 0);
      o1 = __builtin_amdgcn_mfma_f32_16x16x32_bf16(ch ? va11 : va10, pb.s, o1, 0, 0, 0);
    }
  };

  LOADT(akA, bbA, 0);
  for (int t = 0; t < 32; t += 2) {
    LOADT(akB, bbB, (t + 1) * 64);
    STEP(akA, bbA, t * 64);
    if (t + 2 < 32) LOADT(akA, bbA, (t + 2) * 64);
    STEP(akB, bbB, (t + 1) * 64);
  }

  int b = bh >> 3, h = bh & 7;
  float inv = 1.0f / lsum;
  int row = (b * L + q0 + ra) * D + h * HD;
  short4v w0, w1;
#pragma unroll
  for (int r = 0; r < 4; ++r) { w0[r] = f2bf(o0[r] * inv); w1[r] = f2bf(o1[r] * inv); }
  *reinterpret_cast<short4v*>(ob + row + g * 4) = w0;
  *reinterpret_cast<short4v*>(ob + row + 16 + g * 4) = w1;
}

// ---------------- Kernel 3: out = O @ Wout ----------------------------------
__global__ __launch_bounds__(64) void out_gemm(const short* __restrict__ obuf,
                                               const short* __restrict__ wt,
                                               float* __restrict__ out) {
  int bid = blockIdx.x;
  int nt = bid & 3, mt = bid >> 2;
  int m0 = mt * 64, n0 = nt * 64;
  int l = threadIdx.x, ra = l & 15, g = l >> 4;

  f32x4 acc[4][4] = {};
  for (int k0 = 0; k0 < 256; k0 += 32) {
    int kk = k0 + g * 8;
    short8 bfr[4], afr[4];
#pragma unroll
    for (int nf = 0; nf < 4; ++nf)
      bfr[nf] = *reinterpret_cast<const short8*>(&wt[(n0 + nf * 16 + ra) * 256 + kk]);
#pragma unroll
    for (int mf = 0; mf < 4; ++mf)
      afr[mf] = *reinterpret_cast<const short8*>(&obuf[(m0 + mf * 16 + ra) * 256 + kk]);
#pragma unroll
    for (int mf = 0; mf < 4; ++mf)
#pragma unroll
      for (int nf = 0; nf < 4; ++nf)
        acc[mf][nf] = __builtin_amdgcn_mfma_f32_16x16x32_bf16(afr[mf], bfr[nf], acc[mf][nf], 0, 0, 0);
  }
#pragma unroll
  for (int mf = 0; mf < 4; ++mf)
#pragma unroll
    for (int nf = 0; nf < 4; ++nf)
#pragma unroll
      for (int r = 0; r < 4; ++r)
        out[(m0 + mf * 16 + g * 4 + r) * 256 + n0 + nf * 16 + ra] = acc[mf][nf][r];
}

extern "C" void kernel_launch(void* const* d_in, const int* in_sizes, int n_in,
                              void* d_out, int out_size, void* d_ws, size_t ws_size,
                              hipStream_t stream) {
  const float* x    = (const float*)d_in[0];
  const float* bias = (const float*)d_in[1];
  const float* wqkv = (const float*)d_in[2];
  const float* wout = (const float*)d_in[3];
  float* out = (float*)d_out;

  short* xb     = (short*)d_ws;            // [8192,256]   2M shorts
  short* qb     = xb + B * L * D;          // [bh][L][HD]  2M
  short* kb     = qb + B * L * D;          // 2M
  short* vt     = kb + B * L * D;          // [bh][HD][L]  2M
  short* ob     = vt + B * L * D;          // [8192,256]   2M
  short* wqkvT  = ob + B * L * D;          // [768,256]
  short* woutT  = wqkvT + 768 * 256;       // [256,256]

  prep_xb<<<dim3(1024), dim3(256), 0, stream>>>(x, xb);
  prep_wt<<<dim3(8, 24), dim3(256), 0, stream>>>(wqkv, wqkvT, 768);
  prep_wt<<<dim3(8, 8), dim3(256), 0, stream>>>(wout, woutT, 256);
  qkv_gemm<<<dim3(1536), dim3(64), 0, stream>>>(xb, wqkvT, qb, kb, vt);
  attn_fwd<<<dim3(1024), dim3(256), 0, stream>>>(qb, kb, vt, bias, ob);
  out_gemm<<<dim3(512), dim3(64), 0, stream>>>(ob, woutT, out);
}

// Round 4
// 141.120 us; speedup vs baseline: 1.5475x; 1.2981x over previous
//
#include <hip/hip_runtime.h>
#include <hip/hip_bf16.h>
#include <math.h>

#define B 4
#define L 2048
#define D 256
#define H 8
#define HD 32
#define SCALE 0.17677669529663687f
#define LOG2E 1.4426950408889634f
#define QSCL (SCALE * LOG2E)

typedef __attribute__((ext_vector_type(8))) short short8;
typedef __attribute__((ext_vector_type(4))) short short4v;
typedef __attribute__((ext_vector_type(4))) float f32x4;

__device__ inline short f2bf(float x) {
  union { float f; unsigned u; } c; c.f = x;
  unsigned r = (c.u + 0x7FFFu + ((c.u >> 16) & 1u)) >> 16;
  return (short)r;
}

// ---------------- prep: x f32 -> bf16 ---------------------------------------
__global__ __launch_bounds__(256) void prep_xb(const float* __restrict__ x,
                                               short* __restrict__ xb) {
  int i = (blockIdx.x * 256 + threadIdx.x) * 8;
  f32x4 a = *reinterpret_cast<const f32x4*>(x + i);
  f32x4 b = *reinterpret_cast<const f32x4*>(x + i + 4);
  short8 o;
#pragma unroll
  for (int j = 0; j < 4; ++j) { o[j] = f2bf(a[j]); o[4 + j] = f2bf(b[j]); }
  *reinterpret_cast<short8*>(xb + i) = o;
}

// ---------------- prep: W [256,N] f32 -> W^T [N,256] bf16 (LDS tiled) -------
__global__ __launch_bounds__(256) void prep_wt(const float* __restrict__ w,
                                               short* __restrict__ wt, int N) {
  __shared__ short tile[32][33];
  int k0 = blockIdx.x * 32;
  int n0 = blockIdx.y * 32;
  int tx = threadIdx.x & 31, ty = threadIdx.x >> 5;
#pragma unroll
  for (int i = 0; i < 32; i += 8)
    tile[ty + i][tx] = f2bf(w[(k0 + ty + i) * N + n0 + tx]);
  __syncthreads();
#pragma unroll
  for (int i = 0; i < 32; i += 8)
    wt[(n0 + ty + i) * 256 + k0 + tx] = tile[tx][ty + i];
}

// ---------------- Kernel 1: qkv = xb @ Wqkv, head-split outputs -------------
// Q section is pre-scaled by SCALE*LOG2E (softmax runs in exp2 domain).
__global__ __launch_bounds__(64) void qkv_gemm(const short* __restrict__ xb,
                                               const short* __restrict__ wt,
                                               short* __restrict__ qb,
                                               short* __restrict__ kb,
                                               short* __restrict__ vt) {
  int bid = blockIdx.x;
  int mt = bid / 12, nt = bid % 12;
  int m0 = mt * 64, n0 = nt * 64;
  int l = threadIdx.x, ra = l & 15, g = l >> 4;

  f32x4 acc[4][4] = {};
  for (int k0 = 0; k0 < 256; k0 += 32) {
    int kk = k0 + g * 8;
    short8 bfr[4], afr[4];
#pragma unroll
    for (int nf = 0; nf < 4; ++nf)
      bfr[nf] = *reinterpret_cast<const short8*>(&wt[(n0 + nf * 16 + ra) * 256 + kk]);
#pragma unroll
    for (int mf = 0; mf < 4; ++mf)
      afr[mf] = *reinterpret_cast<const short8*>(&xb[(m0 + mf * 16 + ra) * 256 + kk]);
#pragma unroll
    for (int mf = 0; mf < 4; ++mf)
#pragma unroll
      for (int nf = 0; nf < 4; ++nf)
        acc[mf][nf] = __builtin_amdgcn_mfma_f32_16x16x32_bf16(afr[mf], bfr[nf], acc[mf][nf], 0, 0, 0);
  }

  int sec = n0 >> 8;   // 0=q 1=k 2=v (uniform per block)
  float scl = (sec == 0) ? QSCL : 1.0f;
#pragma unroll
  for (int nf = 0; nf < 4; ++nf) {
    int n = n0 + nf * 16 + ra;
    int c = n & 255;
    int h = c >> 5, d = c & 31;
#pragma unroll
    for (int mf = 0; mf < 4; ++mf) {
#pragma unroll
      for (int r = 0; r < 4; ++r) {
        int mm = m0 + mf * 16 + g * 4 + r;
        int b = mm >> 11, lpos = mm & 2047;
        short val = f2bf(acc[mf][nf][r] * scl);
        if (sec == 2) vt[((b * H + h) * HD + d) * L + lpos] = val;
        else {
          short* dst = (sec == 0) ? qb : kb;
          dst[((b * H + h) * L + lpos) * HD + d] = val;
        }
      }
    }
  }
}

// ---------------- Kernel 2: flash attention ---------------------------------
// Block = 4 waves = 4 heads x SAME 64 q-rows (bias L1-shared across waves).
// Wave = 64 q-rows x 1 head: 4 q-tiles share every K/V fragment.
// Grid: bid = qt*8 + hg  ->  XCD = hg: per-XCD K/V working set 1MB, L2-resident.
__global__ __launch_bounds__(256, 1) void attn_fwd(const short* __restrict__ qb,
                                                   const short* __restrict__ kb,
                                                   const short* __restrict__ vt,
                                                   const float* __restrict__ bias,
                                                   short* __restrict__ ob) {
  int wid = threadIdx.x >> 6;
  int l = threadIdx.x & 63;
  int ra = l & 15, g = l >> 4;
  bool oddg = (g & 1);
  int qt = blockIdx.x >> 3;            // 0..31
  int hg = blockIdx.x & 7;             // XCD id; (batch, head-pair) group
  int bh = (hg >> 1) * 8 + (hg & 1) * 4 + wid;
  int q0 = qt * 64;

  const short* kptr = kb + bh * (L * HD) + ra * HD + g * 8;
  const short* vptr0 = vt + bh * (HD * L) + ra * L + g * 8;
  const short* vptr1 = vptr0 + 16 * L;
  const float* bbase = bias + (q0 + ra) * L + g * 4;

  short8 bq[4];
#pragma unroll
  for (int t4 = 0; t4 < 4; ++t4)
    bq[t4] = *reinterpret_cast<const short8*>(qb + (bh * L + q0 + t4 * 16 + ra) * HD + g * 8);

  f32x4 o0[4] = {}, o1[4] = {}, zf = {};
  float mrun[4], lsum[4];
#pragma unroll
  for (int t4 = 0; t4 < 4; ++t4) { mrun[t4] = -1e30f; lsum[t4] = 0.f; }

  short8 akA[4], akB[4], vaA[4], vaB[4];
  f32x4 bbX[2][4], bbY[2][4];

  auto LOADKV = [&](short8 (&ak)[4], short8 (&va)[4], int kv) {
#pragma unroll
    for (int c = 0; c < 4; ++c)
      ak[c] = *reinterpret_cast<const short8*>(kptr + (kv + 16 * c) * HD);
    va[0] = *reinterpret_cast<const short8*>(vptr0 + kv);
    va[1] = *reinterpret_cast<const short8*>(vptr0 + kv + 32);
    va[2] = *reinterpret_cast<const short8*>(vptr1 + kv);
    va[3] = *reinterpret_cast<const short8*>(vptr1 + kv + 32);
  };
  auto BLOAD = [&](f32x4 (&bb)[2][4], int t4base, int kv) {
#pragma unroll
    for (int tt = 0; tt < 2; ++tt)
#pragma unroll
      for (int c = 0; c < 4; ++c)
        bb[tt][c] = *reinterpret_cast<const f32x4*>(bbase + (t4base + tt) * 16 * L + kv + 16 * c);
  };

  auto TILE = [&](int t4, short8 (&ak)[4], short8 (&va)[4], f32x4 (&bb)[4]) {
    f32x4 s0 = __builtin_amdgcn_mfma_f32_16x16x32_bf16(ak[0], bq[t4], zf, 0, 0, 0);
    f32x4 s1 = __builtin_amdgcn_mfma_f32_16x16x32_bf16(ak[1], bq[t4], zf, 0, 0, 0);
    f32x4 s2 = __builtin_amdgcn_mfma_f32_16x16x32_bf16(ak[2], bq[t4], zf, 0, 0, 0);
    f32x4 s3 = __builtin_amdgcn_mfma_f32_16x16x32_bf16(ak[3], bq[t4], zf, 0, 0, 0);

    float v[16];
#pragma unroll
    for (int r = 0; r < 4; ++r) {
      v[r]      = fmaf(bb[0][r], LOG2E, s0[r]);
      v[4 + r]  = fmaf(bb[1][r], LOG2E, s1[r]);
      v[8 + r]  = fmaf(bb[2][r], LOG2E, s2[r]);
      v[12 + r] = fmaf(bb[3][r], LOG2E, s3[r]);
    }
    float pm = v[0];
#pragma unroll
    for (int i = 1; i < 16; ++i) pm = fmaxf(pm, v[i]);
    pm = fmaxf(pm, __shfl_xor(pm, 16));
    pm = fmaxf(pm, __shfl_xor(pm, 32));

    if (!__all(pm <= mrun[t4] + 8.0f)) {
      float mnew = fmaxf(mrun[t4], pm);
      float ad = mrun[t4] - mnew, al;
      asm("v_exp_f32 %0, %1" : "=v"(al) : "v"(ad));
      lsum[t4] *= al;
#pragma unroll
      for (int r = 0; r < 4; ++r) { o0[t4][r] *= al; o1[t4][r] *= al; }
      mrun[t4] = mnew;
    }
    float m = mrun[t4];
#pragma unroll
    for (int i = 0; i < 16; ++i) {
      float x = v[i] - m;
      asm("v_exp_f32 %0, %1" : "=v"(v[i]) : "v"(x));
    }
    float rs = 0.f;
#pragma unroll
    for (int i = 0; i < 16; ++i) rs += v[i];
    rs += __shfl_xor(rs, 16);
    rs += __shfl_xor(rs, 32);
    lsum[t4] += rs;

#pragma unroll
    for (int ch = 0; ch < 2; ++ch) {
      const float* pc = v + ch * 8;
      unsigned w01, w23, w45, w67;
      asm("v_cvt_pk_bf16_f32 %0, %1, %2" : "=v"(w01) : "v"(pc[0]), "v"(pc[1]));
      asm("v_cvt_pk_bf16_f32 %0, %1, %2" : "=v"(w23) : "v"(pc[2]), "v"(pc[3]));
      asm("v_cvt_pk_bf16_f32 %0, %1, %2" : "=v"(w45) : "v"(pc[4]), "v"(pc[5]));
      asm("v_cvt_pk_bf16_f32 %0, %1, %2" : "=v"(w67) : "v"(pc[6]), "v"(pc[7]));
      asm("v_permlane32_swap_b32 %0, %1" : "+v"(w01), "+v"(w45));
      asm("v_permlane32_swap_b32 %0, %1" : "+v"(w23), "+v"(w67));
      unsigned z1 = oddg ? w01 : w45;
      unsigned z2 = oddg ? w23 : w67;
      unsigned y1 = (unsigned)__shfl_xor((int)z1, 16);
      unsigned y2 = (unsigned)__shfl_xor((int)z2, 16);
      union { unsigned u[4]; short8 s; } pb;
      pb.u[0] = oddg ? y1 : w01;
      pb.u[1] = oddg ? y2 : w23;
      pb.u[2] = oddg ? w45 : y1;
      pb.u[3] = oddg ? w67 : y2;
      o0[t4] = __builtin_amdgcn_mfma_f32_16x16x32_bf16(va[ch], pb.s, o0[t4], 0, 0, 0);
      o1[t4] = __builtin_amdgcn_mfma_f32_16x16x32_bf16(va[2 + ch], pb.s, o1[t4], 0, 0, 0);
    }
  };

  LOADKV(akA, vaA, 0);
  BLOAD(bbX, 0, 0);
  for (int t = 0; t < 32; t += 2) {
    LOADKV(akB, vaB, (t + 1) * 64);
    BLOAD(bbY, 2, t * 64);
    TILE(0, akA, vaA, bbX[0]);
    TILE(1, akA, vaA, bbX[1]);
    BLOAD(bbX, 0, (t + 1) * 64);
    TILE(2, akA, vaA, bbY[0]);
    TILE(3, akA, vaA, bbY[1]);
    if (t + 2 < 32) LOADKV(akA, vaA, (t + 2) * 64);
    BLOAD(bbY, 2, (t + 1) * 64);
    TILE(0, akB, vaB, bbX[0]);
    TILE(1, akB, vaB, bbX[1]);
    if (t + 2 < 32) BLOAD(bbX, 0, (t + 2) * 64);
    TILE(2, akB, vaB, bbY[0]);
    TILE(3, akB, vaB, bbY[1]);
  }

  int b = bh >> 3, h = bh & 7;
#pragma unroll
  for (int t4 = 0; t4 < 4; ++t4) {
    float inv = 1.0f / lsum[t4];
    int row = (b * L + q0 + t4 * 16 + ra) * D + h * HD;
    short4v w0, w1;
#pragma unroll
    for (int r = 0; r < 4; ++r) { w0[r] = f2bf(o0[t4][r] * inv); w1[r] = f2bf(o1[t4][r] * inv); }
    *reinterpret_cast<short4v*>(ob + row + g * 4) = w0;
    *reinterpret_cast<short4v*>(ob + row + 16 + g * 4) = w1;
  }
}

// ---------------- Kernel 3: out = O @ Wout ----------------------------------
__global__ __launch_bounds__(64) void out_gemm(const short* __restrict__ obuf,
                                               const short* __restrict__ wt,
                                               float* __restrict__ out) {
  int bid = blockIdx.x;
  int nt = bid & 3, mt = bid >> 2;
  int m0 = mt * 64, n0 = nt * 64;
  int l = threadIdx.x, ra = l & 15, g = l >> 4;

  f32x4 acc[4][4] = {};
  for (int k0 = 0; k0 < 256; k0 += 32) {
    int kk = k0 + g * 8;
    short8 bfr[4], afr[4];
#pragma unroll
    for (int nf = 0; nf < 4; ++nf)
      bfr[nf] = *reinterpret_cast<const short8*>(&wt[(n0 + nf * 16 + ra) * 256 + kk]);
#pragma unroll
    for (int mf = 0; mf < 4; ++mf)
      afr[mf] = *reinterpret_cast<const short8*>(&obuf[(m0 + mf * 16 + ra) * 256 + kk]);
#pragma unroll
    for (int mf = 0; mf < 4; ++mf)
#pragma unroll
      for (int nf = 0; nf < 4; ++nf)
        acc[mf][nf] = __builtin_amdgcn_mfma_f32_16x16x32_bf16(afr[mf], bfr[nf], acc[mf][nf], 0, 0, 0);
  }
#pragma unroll
  for (int mf = 0; mf < 4; ++mf)
#pragma unroll
    for (int nf = 0; nf < 4; ++nf)
#pragma unroll
      for (int r = 0; r < 4; ++r)
        out[(m0 + mf * 16 + g * 4 + r) * 256 + n0 + nf * 16 + ra] = acc[mf][nf][r];
}

extern "C" void kernel_launch(void* const* d_in, const int* in_sizes, int n_in,
                              void* d_out, int out_size, void* d_ws, size_t ws_size,
                              hipStream_t stream) {
  const float* x    = (const float*)d_in[0];
  const float* bias = (const float*)d_in[1];
  const float* wqkv = (const float*)d_in[2];
  const float* wout = (const float*)d_in[3];
  float* out = (float*)d_out;

  short* xb     = (short*)d_ws;            // [8192,256]   2M shorts
  short* qb     = xb + B * L * D;          // [bh][L][HD]  2M
  short* kb     = qb + B * L * D;          // 2M
  short* vt     = kb + B * L * D;          // [bh][HD][L]  2M
  short* ob     = vt + B * L * D;          // [8192,256]   2M
  short* wqkvT  = ob + B * L * D;          // [768,256]
  short* woutT  = wqkvT + 768 * 256;       // [256,256]

  prep_xb<<<dim3(1024), dim3(256), 0, stream>>>(x, xb);
  prep_wt<<<dim3(8, 24), dim3(256), 0, stream>>>(wqkv, wqkvT, 768);
  prep_wt<<<dim3(8, 8), dim3(256), 0, stream>>>(wout, woutT, 256);
  qkv_gemm<<<dim3(1536), dim3(64), 0, stream>>>(xb, wqkvT, qb, kb, vt);
  attn_fwd<<<dim3(256), dim3(256), 0, stream>>>(qb, kb, vt, bias, ob);
  out_gemm<<<dim3(512), dim3(64), 0, stream>>>(ob, woutT, out);
}